// Round 1
// baseline (154.089 us; speedup 1.0000x reference)
//
#include <hip/hip_runtime.h>

// KL(p||q) for diagonal Gaussians, reduced to a single scalar:
// out = (0.5/B) * sum_{b,d} [ (qlv-plv) + exp(plv-qlv) + (pmu-qmu)^2*exp(-qlv) - 1 ]
// Pure memory-bound reduction over 4 x 32MB fp32 arrays.

__global__ __launch_bounds__(256) void kl_reduce_kernel(
    const float4* __restrict__ pmu,
    const float4* __restrict__ plv,
    const float4* __restrict__ qmu,
    const float4* __restrict__ qlv,
    float* __restrict__ out,
    int n4, float scale) {
  float acc = 0.0f;
  const int stride = gridDim.x * blockDim.x;
  for (int i = blockIdx.x * blockDim.x + threadIdx.x; i < n4; i += stride) {
    const float4 a = pmu[i];
    const float4 b = plv[i];
    const float4 c = qmu[i];
    const float4 d = qlv[i];

    float dx, lr;
    lr = d.x - b.x; dx = a.x - c.x;
    acc += lr + __expf(-lr) + dx * dx * __expf(-d.x) - 1.0f;
    lr = d.y - b.y; dx = a.y - c.y;
    acc += lr + __expf(-lr) + dx * dx * __expf(-d.y) - 1.0f;
    lr = d.z - b.z; dx = a.z - c.z;
    acc += lr + __expf(-lr) + dx * dx * __expf(-d.z) - 1.0f;
    lr = d.w - b.w; dx = a.w - c.w;
    acc += lr + __expf(-lr) + dx * dx * __expf(-d.w) - 1.0f;
  }

  // wave-64 butterfly reduce
  #pragma unroll
  for (int off = 32; off > 0; off >>= 1)
    acc += __shfl_down(acc, off, 64);

  __shared__ float sm[4];  // 256 threads / 64 lanes = 4 waves
  const int lane = threadIdx.x & 63;
  const int wid  = threadIdx.x >> 6;
  if (lane == 0) sm[wid] = acc;
  __syncthreads();
  if (threadIdx.x == 0) {
    const float blocksum = sm[0] + sm[1] + sm[2] + sm[3];
    atomicAdd(out, blocksum * scale);  // device-scope by default on CDNA
  }
}

extern "C" void kernel_launch(void* const* d_in, const int* in_sizes, int n_in,
                              void* d_out, int out_size, void* d_ws, size_t ws_size,
                              hipStream_t stream) {
  const float* pmu = (const float*)d_in[0];
  const float* plv = (const float*)d_in[1];
  const float* qmu = (const float*)d_in[2];
  const float* qlv = (const float*)d_in[3];
  float* out = (float*)d_out;

  const int n = in_sizes[0];            // 16384*512 = 8388608
  const int B = 16384;
  const int n4 = n / 4;                 // 2097152 float4 per array
  const float scale = 0.5f / (float)B;

  // d_out is poisoned to 0xAA before every launch; zero it on-stream.
  hipMemsetAsync(d_out, 0, sizeof(float), stream);

  const int block = 256;
  const int grid = 2048;                // 8 blocks/CU, grid-stride covers n4
  kl_reduce_kernel<<<grid, block, 0, stream>>>(
      (const float4*)pmu, (const float4*)plv, (const float4*)qmu,
      (const float4*)qlv, out, n4, scale);
}